// Round 1
// baseline (76.199 us; speedup 1.0000x reference)
//
#include <hip/hip_runtime.h>
#include <math.h>

#define W_IMG 512
#define H_IMG 512
#define ALPHA_MIN (1.0f/255.0f)
#define ALPHA_MAX 0.999f

// One thread per pixel of a 16x16 tile; 256 threads/block; grid 32x32.
// Per 256-gaussian chunk: cooperative param compute + tile-cull +
// ballot/popcount compaction into LDS, then all pixels iterate the
// compacted list (LDS broadcast reads, conflict-free).
__global__ __launch_bounds__(256) void splat_render(
    const float* __restrict__ xyz,
    const float* __restrict__ scaling,
    const float* __restrict__ rotation,
    const float* __restrict__ features,
    const float* __restrict__ opacity,
    float* __restrict__ out, int N)
{
  __shared__ float4 sA[256];   // mx, my, h0(=0.5*c0), h1(=c1)
  __shared__ float4 sB[256];   // h2(=0.5*c2), f0, f1, f2
  __shared__ float  sOp[256];  // opacity
  __shared__ int wave_base[4];
  __shared__ int s_total;

  const int tid = threadIdx.x;
  const int tile_x = blockIdx.x << 4;
  const int tile_y = blockIdx.y << 4;
  const int lx = tid & 15, ly = tid >> 4;
  const float px = (float)(tile_x + lx);
  const float py = (float)(tile_y + ly);
  const float tx0 = (float)tile_x, tx1 = (float)(tile_x + 15);
  const float ty0 = (float)tile_y, ty1 = (float)(tile_y + 15);

  float acc0 = 0.f, acc1 = 0.f, acc2 = 0.f;

  for (int base = 0; base < N; base += 256) {
    const int gi = base + tid;
    bool keep = false;
    float mx=0.f,my=0.f,h0=0.f,h1=0.f,h2=0.f,op=0.f,f0=0.f,f1=0.f,f2=0.f;
    if (gi < N) {
      const float rx = rotation[gi];
      const float theta = 6.28318530717958647692f / (1.0f + __expf(-rx));
      float sn, cs;
      __sincosf(theta, &sn, &cs);
      const float sxa = fabsf(scaling[2*gi+0]);
      const float sya = fabsf(scaling[2*gi+1]);
      const float s0 = sxa*sxa, s1 = sya*sya;
      const float a = cs*cs*s0 + sn*sn*s1;
      const float b = cs*sn*(s0 - s1);
      const float c = sn*sn*s0 + cs*cs*s1;
      const float inv_det = 1.0f / (a*c - b*b);
      h0 = 0.5f * c * inv_det;      // 0.5*c0
      h1 = -b * inv_det;            // c1
      h2 = 0.5f * a * inv_det;      // 0.5*c2
      mx = 0.5f*((xyz[2*gi+0] + 1.0f)*(float)W_IMG - 1.0f);
      my = 0.5f*((xyz[2*gi+1] + 1.0f)*(float)H_IMG - 1.0f);
      op = opacity[gi];
      f0 = features[3*gi+0]; f1 = features[3*gi+1]; f2 = features[3*gi+2];
      // Cull: visible needs sigma <= ln(255*op); sigma >= |d|^2 / (2*max(s0,s1))
      // (eigenvalues of the covariance are exactly s0, s1).
      if (op > 0.0f) {
        const float T = __logf(255.0f * op);
        if (T > 0.0f) {
          const float r2 = 2.0f * T * fmaxf(s0, s1) * 1.0001f + 1e-2f;
          const float ddx = fmaxf(fmaxf(tx0 - mx, mx - tx1), 0.0f);
          const float ddy = fmaxf(fmaxf(ty0 - my, my - ty1), 0.0f);
          keep = (ddx*ddx + ddy*ddy) <= r2;
        }
      }
    }
    // ballot-compact survivors into LDS
    const unsigned long long m = __ballot(keep);
    const int lane = tid & 63, wid = tid >> 6;
    const int pre = __popcll(m & ((1ull << lane) - 1ull));
    if (lane == 0) wave_base[wid] = __popcll(m);
    __syncthreads();
    if (tid == 0) {
      int s = 0;
      #pragma unroll
      for (int w = 0; w < 4; ++w) { const int cw = wave_base[w]; wave_base[w] = s; s += cw; }
      s_total = s;
    }
    __syncthreads();
    if (keep) {
      const int p = wave_base[wid] + pre;
      sA[p] = make_float4(mx, my, h0, h1);
      sB[p] = make_float4(h2, f0, f1, f2);
      sOp[p] = op;
    }
    __syncthreads();
    const int cnt = s_total;
    for (int j = 0; j < cnt; ++j) {
      const float4 gA = sA[j];
      const float4 gB = sB[j];
      const float opj = sOp[j];
      const float dx = px - gA.x;
      const float dy = py - gA.y;
      const float sig = fmaf(dx, fmaf(gA.z, dx, gA.w*dy), gB.x*dy*dy);
      const float e = __expf(-sig);
      float alpha = fminf(ALPHA_MAX, opj * e);
      alpha = (alpha < ALPHA_MIN) ? 0.0f : alpha;
      acc0 = fmaf(alpha, gB.y, acc0);
      acc1 = fmaf(alpha, gB.z, acc1);
      acc2 = fmaf(alpha, gB.w, acc2);
    }
    __syncthreads();
  }

  const int x = tile_x + lx, y = tile_y + ly;
  const int pix = y * W_IMG + x;
  out[pix]                 = fminf(fmaxf(acc0, 0.0f), 1.0f);
  out[W_IMG*H_IMG + pix]   = fminf(fmaxf(acc1, 0.0f), 1.0f);
  out[2*W_IMG*H_IMG + pix] = fminf(fmaxf(acc2, 0.0f), 1.0f);
}

extern "C" void kernel_launch(void* const* d_in, const int* in_sizes, int n_in,
                              void* d_out, int out_size, void* d_ws, size_t ws_size,
                              hipStream_t stream) {
  const float* xyz      = (const float*)d_in[0];
  const float* scaling  = (const float*)d_in[1];
  const float* rotation = (const float*)d_in[2];
  const float* features = (const float*)d_in[3];
  const float* opacity  = (const float*)d_in[4];
  float* out = (float*)d_out;
  const int N = in_sizes[0] / 2;
  dim3 grid(W_IMG / 16, H_IMG / 16);
  splat_render<<<grid, 256, 0, stream>>>(xyz, scaling, rotation, features, opacity, out, N);
}

// Round 2
// 73.879 us; speedup vs baseline: 1.0314x; 1.0314x over previous
//
#include <hip/hip_runtime.h>
#include <math.h>

#define W_IMG 512
#define H_IMG 512
#define ALPHA_MIN (1.0f/255.0f)
#define ALPHA_MAX 0.999f
#define NMAX_CHUNK 256

// ---------------- Kernel 1: per-gaussian parameter precompute ----------------
// One thread per gaussian. All transcendentals (sigmoid, sincos, log) and the
// precise divide happen exactly once per gaussian instead of once per
// (gaussian, tile) pair (1024x redundancy in the previous version).
// Output SoA in d_ws (coalesced float4):
//   G0[i] = (mx, my, h0=0.5*c0, h1=c1)
//   G1[i] = (h2=0.5*c2, r2_cull, op, 0)
//   G2[i] = (f0, f1, f2, 0)
__global__ __launch_bounds__(256) void precompute_params(
    const float* __restrict__ xyz,
    const float* __restrict__ scaling,
    const float* __restrict__ rotation,
    const float* __restrict__ features,
    const float* __restrict__ opacity,
    float4* __restrict__ G0, float4* __restrict__ G1, float4* __restrict__ G2,
    int N)
{
  const int i = blockIdx.x * 256 + threadIdx.x;
  if (i >= N) return;
  const float rx = rotation[i];
  const float theta = 6.28318530717958647692f / (1.0f + __expf(-rx));
  float sn, cs;
  __sincosf(theta, &sn, &cs);
  const float sxa = fabsf(scaling[2*i+0]);
  const float sya = fabsf(scaling[2*i+1]);
  const float s0 = sxa*sxa, s1 = sya*sya;
  const float a = cs*cs*s0 + sn*sn*s1;
  const float b = cs*sn*(s0 - s1);
  const float c = sn*sn*s0 + cs*cs*s1;
  const float inv_det = 1.0f / (a*c - b*b);
  const float h0 = 0.5f * c * inv_det;
  const float h1 = -b * inv_det;
  const float h2 = 0.5f * a * inv_det;
  const float mx = 0.5f*((xyz[2*i+0] + 1.0f)*(float)W_IMG - 1.0f);
  const float my = 0.5f*((xyz[2*i+1] + 1.0f)*(float)H_IMG - 1.0f);
  const float op = opacity[i];
  // Visible only where sigma <= ln(255*op); sigma >= |d|^2/(2*max(s0,s1))
  // since the covariance eigenvalues are exactly s0, s1.
  float r2 = -1.0f;  // negative => never visible
  if (op > 0.0f) {
    const float T = __logf(255.0f * op);
    if (T > 0.0f) r2 = 2.0f * T * fmaxf(s0, s1) * 1.0001f + 1e-2f;
  }
  G0[i] = make_float4(mx, my, h0, h1);
  G1[i] = make_float4(h2, r2, op, 0.0f);
  G2[i] = make_float4(features[3*i+0], features[3*i+1], features[3*i+2], 0.0f);
}

// ---------------- Kernel 2: tiled render ----------------
// 16x16 pixel tile per block, 1 thread/pixel. Per 256-gaussian chunk:
// coalesced float4 param loads + rect-distance cull + ballot compaction into
// LDS, then all pixels iterate the compacted list (broadcast LDS reads).
__global__ __launch_bounds__(256) void splat_render(
    const float4* __restrict__ G0,
    const float4* __restrict__ G1,
    const float4* __restrict__ G2,
    float* __restrict__ out, int N)
{
  __shared__ float4 sA[NMAX_CHUNK];   // mx, my, h0, h1
  __shared__ float4 sB[NMAX_CHUNK];   // h2, f0, f1, f2
  __shared__ float  sOp[NMAX_CHUNK];
  __shared__ int wcnt[4];

  const int tid = threadIdx.x;
  const int tile_x = blockIdx.x << 4;
  const int tile_y = blockIdx.y << 4;
  const int lx = tid & 15, ly = tid >> 4;
  const float px = (float)(tile_x + lx);
  const float py = (float)(tile_y + ly);
  const float tx0 = (float)tile_x, tx1 = (float)(tile_x + 15);
  const float ty0 = (float)tile_y, ty1 = (float)(tile_y + 15);

  float acc0 = 0.f, acc1 = 0.f, acc2 = 0.f;

  for (int base = 0; base < N; base += NMAX_CHUNK) {
    const int gi = base + tid;
    bool keep = false;
    float4 g0 = make_float4(0,0,0,0), g1 = make_float4(0,0,0,0), g2 = make_float4(0,0,0,0);
    if (gi < N) {
      g0 = G0[gi]; g1 = G1[gi]; g2 = G2[gi];
      const float ddx = fmaxf(fmaxf(tx0 - g0.x, g0.x - tx1), 0.0f);
      const float ddy = fmaxf(fmaxf(ty0 - g0.y, g0.y - ty1), 0.0f);
      keep = (ddx*ddx + ddy*ddy) <= g1.y;
    }
    // ballot-compact survivors into LDS (one barrier for the count exchange)
    const unsigned long long m = __ballot(keep);
    const int lane = tid & 63, wid = tid >> 6;
    const int pre = __popcll(m & ((1ull << lane) - 1ull));
    if (lane == 0) wcnt[wid] = __popcll(m);
    __syncthreads();
    int wbase = 0, total = 0;
    #pragma unroll
    for (int w = 0; w < 4; ++w) { const int cw = wcnt[w]; if (w < wid) wbase += cw; total += cw; }
    if (keep) {
      const int p = wbase + pre;
      sA[p] = make_float4(g0.x, g0.y, g0.z, g0.w);
      sB[p] = make_float4(g1.x, g2.x, g2.y, g2.z);
      sOp[p] = g1.z;
    }
    __syncthreads();
    for (int j = 0; j < total; ++j) {
      const float4 gA = sA[j];
      const float4 gB = sB[j];
      const float opj = sOp[j];
      const float dx = px - gA.x;
      const float dy = py - gA.y;
      const float sig = fmaf(dx, fmaf(gA.z, dx, gA.w*dy), gB.x*dy*dy);
      const float e = __expf(-sig);
      float alpha = fminf(ALPHA_MAX, opj * e);
      alpha = (alpha < ALPHA_MIN) ? 0.0f : alpha;
      acc0 = fmaf(alpha, gB.y, acc0);
      acc1 = fmaf(alpha, gB.z, acc1);
      acc2 = fmaf(alpha, gB.w, acc2);
    }
    __syncthreads();   // protect wcnt/sA before next chunk overwrites
  }

  const int x = tile_x + lx, y = tile_y + ly;
  const int pix = y * W_IMG + x;
  out[pix]                 = fminf(fmaxf(acc0, 0.0f), 1.0f);
  out[W_IMG*H_IMG + pix]   = fminf(fmaxf(acc1, 0.0f), 1.0f);
  out[2*W_IMG*H_IMG + pix] = fminf(fmaxf(acc2, 0.0f), 1.0f);
}

extern "C" void kernel_launch(void* const* d_in, const int* in_sizes, int n_in,
                              void* d_out, int out_size, void* d_ws, size_t ws_size,
                              hipStream_t stream) {
  const float* xyz      = (const float*)d_in[0];
  const float* scaling  = (const float*)d_in[1];
  const float* rotation = (const float*)d_in[2];
  const float* features = (const float*)d_in[3];
  const float* opacity  = (const float*)d_in[4];
  float* out = (float*)d_out;
  const int N = in_sizes[0] / 2;

  char* ws = (char*)d_ws;
  float4* G0 = (float4*)(ws);
  float4* G1 = (float4*)(ws + 16*2048);
  float4* G2 = (float4*)(ws + 32*2048);

  precompute_params<<<(N + 255)/256, 256, 0, stream>>>(
      xyz, scaling, rotation, features, opacity, G0, G1, G2, N);
  dim3 grid(W_IMG / 16, H_IMG / 16);
  splat_render<<<grid, 256, 0, stream>>>(G0, G1, G2, out, N);
}